// Round 1
// 30285.944 us; speedup vs baseline: 1.1568x; 1.1568x over previous
//
#include <hip/hip_runtime.h>
#include <stdint.h>

// TLSTM: batch-1 LSTM, T=16384 steps, IN=512, H=1024, OUT=64.
// Persistent-kernel design: 256 WGs (one per CU). WG b owns h-elements
// {4b..4b+3}; wave w of the WG owns element 4b+w and computes all 4 gate
// rows for it. All weights for those rows live in per-lane REGISTERS
// (96 floats/lane), loaded once. Cross-WG exchange of h each step goes
// through a tagged 64-bit {step, value} word per h-element in d_ws.
// Double-buffered by step parity (all-to-all dependency bounds skew to
// 1 step, so 2 buffers suffice).
//
// R1 change: the poll loop previously issued 4 strided 8B device-scope
// atomic loads per thread per sweep -> 512 L3 line-requests per WG-sweep
// (each line re-requested 4x). Now each thread reads its 4 contiguous
// tagged words (32B) with two coalesced global_load_dwordx4 sc0 sc1
// cache-bypass loads -> 128 line-requests per WG-sweep, each line once.
// Tag+value pairs are 8B-aligned within a line, so a 16B read cannot
// tear a pair (producer stores each pair with a single 8B store).

typedef unsigned long long u64;
typedef uint32_t u32x4 __attribute__((ext_vector_type(4)));

#define T_STEPS 16384
#define IN_DIM  512
#define H_DIM   1024
#define OUT_DIM 64
#define NWG     256

__device__ __forceinline__ float sigf(float x) {
    return 1.0f / (1.0f + __expf(-x));
}
__device__ __forceinline__ float tanh_fast(float x) {
    // tanh(x) = 2*sigmoid(2x) - 1 ; |err| ~1e-7 rel with __expf
    return 2.0f / (1.0f + __expf(-2.0f * x)) - 1.0f;
}

__global__ __launch_bounds__(256, 1) void lstm_seq(
    const float* __restrict__ X,
    const float* __restrict__ W_ih,
    const float* __restrict__ W_hh,
    const float* __restrict__ b_ih,
    const float* __restrict__ b_hh,
    u64* __restrict__ hbuf)   // [2][H_DIM] tagged words in d_ws
{
    const int b    = blockIdx.x;      // 0..255
    const int tid  = threadIdx.x;     // 0..255
    const int w    = tid >> 6;        // wave id == owned element index j
    const int lane = tid & 63;
    const int elem = 4 * b + w;       // global h index this wave produces

    __shared__ float h_lds[2][H_DIM];
    __shared__ float x_lds[2][IN_DIM];

    // ---- one-time: weights into registers ----
    // lane covers k = c*256 + lane*4 + {0..3}  (contiguous float4, coalesced
    // global loads and conflict-free ds_read_b128 later).
    float4 wh[4][4];   // [gate][chunk]  over H_DIM=1024
    float4 wx[4][2];   // [gate][chunk]  over IN_DIM=512
    float  bias_g[4];
    #pragma unroll
    for (int g = 0; g < 4; ++g) {
        const int row = g * H_DIM + elem;
        #pragma unroll
        for (int c = 0; c < 4; ++c)
            wh[g][c] = *(const float4*)(W_hh + (size_t)row * H_DIM + (c * 256 + lane * 4));
        #pragma unroll
        for (int c = 0; c < 2; ++c)
            wx[g][c] = *(const float4*)(W_ih + (size_t)row * IN_DIM + (c * 256 + lane * 4));
        bias_g[g] = b_ih[row] + b_hh[row];
    }

    // per-thread poll bases for the two parity buffers (4 tagged words = 32B)
    const uint32_t* poll0 = (const uint32_t*)(hbuf + (size_t)tid * 4);
    const uint32_t* poll1 = (const uint32_t*)(hbuf + (size_t)H_DIM + (size_t)tid * 4);

    float c_state = 0.0f;   // cell state for `elem` (consistent across lanes)

    for (int t = 0; t < T_STEPS; ++t) {
        const int p = t & 1;

        // ---- stage x[t] into LDS (issue global load before the spin) ----
        const float2 xv = *(const float2*)(X + (size_t)t * IN_DIM + tid * 2);
        *(float2*)(&x_lds[p][tid * 2]) = xv;

        // ---- poll h[t]: 4 tagged words per thread, coalesced 2x16B reads ----
        {
            const uint32_t* src = p ? poll1 : poll0;
            const uint32_t tu = (uint32_t)t;
            u32x4 a, b4;
            for (;;) {
                asm volatile(
                    "global_load_dwordx4 %0, %2, off sc0 sc1\n\t"
                    "global_load_dwordx4 %1, %2, off offset:16 sc0 sc1\n\t"
                    "s_waitcnt vmcnt(0)"
                    : "=&v"(a), "=&v"(b4)
                    : "v"(src)
                    : "memory");
                // dwords: [val0, tag0, val1, tag1]
                if ((((a[1] ^ tu) | (a[3] ^ tu)) | ((b4[1] ^ tu) | (b4[3] ^ tu))) == 0u)
                    break;
            }
            h_lds[p][tid * 4 + 0] = __uint_as_float(a[0]);
            h_lds[p][tid * 4 + 1] = __uint_as_float(a[2]);
            h_lds[p][tid * 4 + 2] = __uint_as_float(b4[0]);
            h_lds[p][tid * 4 + 3] = __uint_as_float(b4[2]);
        }
        __syncthreads();   // single barrier per step: staging complete

        // ---- 4 gate dot-products for `elem` ----
        float acc0 = 0.f, acc1 = 0.f, acc2 = 0.f, acc3 = 0.f;
        const float4* h4 = (const float4*)(&h_lds[p][0]);
        const float4* x4 = (const float4*)(&x_lds[p][0]);
        #pragma unroll
        for (int c = 0; c < 4; ++c) {
            const float4 hv = h4[c * 64 + lane];
            acc0 += wh[0][c].x*hv.x + wh[0][c].y*hv.y + wh[0][c].z*hv.z + wh[0][c].w*hv.w;
            acc1 += wh[1][c].x*hv.x + wh[1][c].y*hv.y + wh[1][c].z*hv.z + wh[1][c].w*hv.w;
            acc2 += wh[2][c].x*hv.x + wh[2][c].y*hv.y + wh[2][c].z*hv.z + wh[2][c].w*hv.w;
            acc3 += wh[3][c].x*hv.x + wh[3][c].y*hv.y + wh[3][c].z*hv.z + wh[3][c].w*hv.w;
        }
        #pragma unroll
        for (int c = 0; c < 2; ++c) {
            const float4 qv = x4[c * 64 + lane];
            acc0 += wx[0][c].x*qv.x + wx[0][c].y*qv.y + wx[0][c].z*qv.z + wx[0][c].w*qv.w;
            acc1 += wx[1][c].x*qv.x + wx[1][c].y*qv.y + wx[1][c].z*qv.z + wx[1][c].w*qv.w;
            acc2 += wx[2][c].x*qv.x + wx[2][c].y*qv.y + wx[2][c].z*qv.z + wx[2][c].w*qv.w;
            acc3 += wx[3][c].x*qv.x + wx[3][c].y*qv.y + wx[3][c].z*qv.z + wx[3][c].w*qv.w;
        }

        // ---- full-wave butterfly reduce (all lanes end with the sums) ----
        #pragma unroll
        for (int off = 32; off >= 1; off >>= 1) {
            acc0 += __shfl_xor(acc0, off);
            acc1 += __shfl_xor(acc1, off);
            acc2 += __shfl_xor(acc2, off);
            acc3 += __shfl_xor(acc3, off);
        }

        // ---- combine (all lanes compute; avoids divergent exec region) ----
        const float ii = sigf(acc0 + bias_g[0]);
        const float ff = sigf(acc1 + bias_g[1]);
        const float gg = tanh_fast(acc2 + bias_g[2]);
        const float oo = sigf(acc3 + bias_g[3]);
        const float cn = ff * c_state + ii * gg;
        c_state = cn;
        const float hn = oo * tanh_fast(cn);

        if (lane == 0) {
            const u64 word = ((u64)(unsigned)(t + 1) << 32)
                           | (u64)__float_as_uint(hn);
            __hip_atomic_store(hbuf + (size_t)((t + 1) & 1) * H_DIM + elem,
                               word, __ATOMIC_RELAXED, __HIP_MEMORY_SCOPE_AGENT);
        }
        // No second barrier needed: next-step staging writes parity (t+1)&1,
        // disjoint from this step's reads; tag protocol covers parity reuse.
    }
}

__global__ __launch_bounds__(256, 1) void lstm_head(
    const u64* __restrict__ hbuf,
    const float* __restrict__ W_lin,
    const float* __restrict__ b_lin,
    float* __restrict__ out)
{
    const int tid  = threadIdx.x;
    const int o    = tid >> 2;       // output index, 4 threads per output
    const int part = tid & 3;
    const u64* src = hbuf + (size_t)(T_STEPS & 1) * H_DIM;  // buf[0]: tag T

    float sum = 0.f;
    const int k0 = part * 256;
    for (int k = k0; k < k0 + 256; k += 4) {
        const float4 wv = *(const float4*)(W_lin + (size_t)o * H_DIM + k);
        sum += wv.x * __uint_as_float((unsigned)src[k + 0])
             + wv.y * __uint_as_float((unsigned)src[k + 1])
             + wv.z * __uint_as_float((unsigned)src[k + 2])
             + wv.w * __uint_as_float((unsigned)src[k + 3]);
    }
    sum += __shfl_xor(sum, 1);
    sum += __shfl_xor(sum, 2);
    if (part == 0)
        out[o] = 1.0f / (1.0f + __expf(-(sum + b_lin[o])));
}

extern "C" void kernel_launch(void* const* d_in, const int* in_sizes, int n_in,
                              void* d_out, int out_size, void* d_ws, size_t ws_size,
                              hipStream_t stream) {
    const float* X     = (const float*)d_in[0];
    // d_in[1] Mask, d_in[2] Delta, d_in[3] dt: unused by the forward pass
    const float* W_ih  = (const float*)d_in[4];
    const float* W_hh  = (const float*)d_in[5];
    const float* b_ih  = (const float*)d_in[6];
    const float* b_hh  = (const float*)d_in[7];
    const float* W_lin = (const float*)d_in[8];
    const float* b_lin = (const float*)d_in[9];
    float* out = (float*)d_out;

    u64* hbuf = (u64*)d_ws;   // 2 * 1024 * 8B = 16 KiB used

    // init: both parity buffers = {tag=0, h=0.0f} (all zero bytes)
    hipMemsetAsync(hbuf, 0, 2 * H_DIM * sizeof(u64), stream);

    lstm_seq<<<NWG, 256, 0, stream>>>(X, W_ih, W_hh, b_ih, b_hh, hbuf);
    lstm_head<<<1, 256, 0, stream>>>(hbuf, W_lin, b_lin, out);
}